// Round 1
// 1331.351 us; speedup vs baseline: 1.0088x; 1.0088x over previous
//
#include <hip/hip_runtime.h>

// out[b,t,v] = sum_d x[b,t,d,v]*w[d] + bias
// x: (B=2, T=512, D=8, V=32000) fp32, contiguous in v.
// Mandatory traffic: 1.049 GB read + 131 MB write -> ~190 us floor at 6.3 TB/s.
//
// Structure: grid (2, 1024). Each block = one bt row x half the v range.
// 2048 blocks x 4 waves = 8 blocks/CU = 32 waves/CU: every block resident,
// no block churn. Each block advances 8 contiguous read streams (one per d,
// 64 KB each) + 1 contiguous write stream -> DRAM page-hit friendly.
// All data is stream-once: nontemporal loads/stores (nt flag) skip
// cache-allocate overhead.

constexpr int V  = 32000;
constexpr int D  = 8;
constexpr int V4 = V / 4;              // 8000 float4 groups per (bt, d) row
constexpr int HALVES = 2;
constexpr int V4_PER_BLOCK = V4 / HALVES;  // 4000
constexpr int BLOCK = 256;

typedef float f32x4 __attribute__((ext_vector_type(4)));

__global__ __launch_bounds__(BLOCK)
void ttm_kernel(const float* __restrict__ x,
                const float* __restrict__ w,
                const float* __restrict__ bias,
                float* __restrict__ out) {
    const int bt   = blockIdx.y;                 // 0 .. B*T-1
    const int base = blockIdx.x * V4_PER_BLOCK;  // v4 offset of this block's half

    // weights: uniform-address loads (scalarized by compiler), 8 floats
    const f32x4 w03 = *(const f32x4*)(w);
    const f32x4 w47 = *(const f32x4*)(w + 4);
    const float bb  = bias[0];
    const float wd[D] = {w03.x, w03.y, w03.z, w03.w, w47.x, w47.y, w47.z, w47.w};

    const float* xrow = x   + (size_t)bt * (D * V);
    float*       orow = out + (size_t)bt * V;

    // contiguous march over this block's v-range: t advances by BLOCK*16 B
    // per iteration -> each of the 9 streams is sequential in memory.
    for (int t = threadIdx.x; t < V4_PER_BLOCK; t += BLOCK) {
        const int v4i = base + t;
        const float* p = xrow + (size_t)v4i * 4;

        f32x4 acc = {bb, bb, bb, bb};
#pragma unroll
        for (int d = 0; d < D; ++d) {
            const f32x4 xv = __builtin_nontemporal_load((const f32x4*)(p + (size_t)d * V));
            acc += xv * wd[d];
        }
        __builtin_nontemporal_store(acc, (f32x4*)(orow + (size_t)v4i * 4));
    }
}

extern "C" void kernel_launch(void* const* d_in, const int* in_sizes, int n_in,
                              void* d_out, int out_size, void* d_ws, size_t ws_size,
                              hipStream_t stream) {
    const float* x    = (const float*)d_in[0];  // (2,512,8,32000)
    const float* w    = (const float*)d_in[1];  // (8,)
    const float* bias = (const float*)d_in[2];  // (1,)
    float* out        = (float*)d_out;          // (2,512,32000)

    const int nbt = 2 * 512;
    dim3 block(BLOCK, 1, 1);
    dim3 grid(HALVES, nbt, 1);                  // (2, 1024) = 2048 blocks
    ttm_kernel<<<grid, block, 0, stream>>>(x, w, bias, out);
}